// Round 6
// baseline (160.035 us; speedup 1.0000x reference)
//
#include <hip/hip_runtime.h>

// Reference collapses: softmax row-sums are exactly 1, and einsum 'bqk,bvd->bqd'
// contracts k and v independently, so out[b,q,d] = sum_n v[b,n,d] (q-independent).
//   colsum[b,ch] = sum_n GN(x)[b,n,ch]   (phase 1, per-group atomics)
//   S[b,d]       = dot(Wv[d,:], colsum[b,:]) + 1024*bv[d]          (phase 2)
//   out[b,d,:]   = dot(Wo[d,:], S[b,:]) + bo[d]  broadcast over hw (phase 3)
// Wq/bq/Wk/bk are provably dead (they only enter via softmax row-sum == 1).
//
// Round 6. Round 5: 48us kernel, occupancy 34%, VALUBusy 9%, HBM 28% — still
// latency-bound, and occupancy is hard-capped by the grid (512 blocks x 8
// waves = 16 waves/CU = 50% of the 32-wave capacity). This round keeps the
// proven fence-free per-batch barrier structure EXACTLY (512 blocks, 32
// arrivals per batch) and doubles resident waves: 1024 threads/block ->
// 2 blocks/CU x 16 waves = 32 waves/CU (100%). __launch_bounds__(1024,8)
// (8 waves/EU => 2 blocks/CU) caps VGPR at 64; round-5 build used 56.
// Phase 1 issues all 8 of a thread's loads back-to-back before first use.

#define BATCH 16
#define CH    1024
#define NHW   1024
#define G     32
#define NPG   32
#define EPG   (NPG*CH)
#define EPSV  1e-5f
#define GRID  (BATCH*G)   // 512 blocks = 2/CU, co-resident (rounds 2/4/5 empirical)
#define TPB   1024

__device__ __forceinline__ void coh_store_f32(float* p, float v) {
    __hip_atomic_store((unsigned*)p, __float_as_uint(v), __ATOMIC_RELAXED, __HIP_MEMORY_SCOPE_AGENT);
}
// coherent 8-byte load (2 floats), bypassing potentially-stale L1/L2
__device__ __forceinline__ void coh_load_f32x2(const float* p, float* d0, float* d1) {
    unsigned long long u = __hip_atomic_load((const unsigned long long*)p,
                                             __ATOMIC_RELAXED, __HIP_MEMORY_SCOPE_AGENT);
    *d0 = __uint_as_float((unsigned)(u & 0xffffffffu));
    *d1 = __uint_as_float((unsigned)(u >> 32));
}

// Fence-free per-batch barrier: relaxed arrive + relaxed poll by thread 0.
// __syncthreads() emits s_waitcnt vmcnt(0) before s_barrier, so every thread's
// coherent/atomic writes have reached the coherence point before the arrive.
__device__ __forceinline__ void batch_barrier(int* ctr, int expected)
{
    __syncthreads();
    if (threadIdx.x == 0) {
        __hip_atomic_fetch_add(ctr, 1, __ATOMIC_RELAXED, __HIP_MEMORY_SCOPE_AGENT);
        while (__hip_atomic_load(ctr, __ATOMIC_RELAXED, __HIP_MEMORY_SCOPE_AGENT) < expected)
            __builtin_amdgcn_s_sleep(1);
    }
    __syncthreads();
}

__global__ __launch_bounds__(TPB, 8) void fused_all(
    const float* __restrict__ x, const float* __restrict__ gamma,
    const float* __restrict__ beta,
    const float* __restrict__ Wv, const float* __restrict__ bv,
    const float* __restrict__ Wo, const float* __restrict__ bo,
    float* __restrict__ colsum, float* __restrict__ S,
    float* __restrict__ out, int* __restrict__ bar0, int* __restrict__ bar1)
{
    const int blk  = blockIdx.x;
    const int t    = threadIdx.x;
    const int lane = t & 63, wave = t >> 6;   // 16 waves
    const int b    = blk >> 5;                // batch: same meaning in all phases

    __shared__ float smem[CH];                // pch (p1) / cs (p2) / sv (p3)
    __shared__ float r1[16], r2[16], rb[16];

    // ---- phase 1: GN stats + colsum contribution (block = (b, g)) ----
    // Same math as the harness-verified k1_fused, 1024 threads: c0 covers 128
    // channels, 8 ch-iterations per thread, ALL 8 loads issued before use.
    {
        const int g  = blk & 31;
        const int n4 = t & 7;                 // which float4 of the group's 32 n's
        const int c0 = t >> 3;                // starting channel 0..127

        const float4* xg = reinterpret_cast<const float4*>(x + (size_t)b * (CH * NHW) + g * NPG);
        const float4  gm = reinterpret_cast<const float4*>(gamma + g * NPG)[n4];

        float4 vb[8];
        #pragma unroll
        for (int k = 0; k < 8; k++)           // 8 independent loads in flight
            vb[k] = xg[(c0 + k * 128) * (NHW / 4) + n4];

        float s1 = 0.f, s2 = 0.f;
        #pragma unroll
        for (int k = 0; k < 8; k++) {
            const float4 v = vb[k];
            const int ch = c0 + k * 128;
            s1 += v.x + v.y + v.z + v.w;
            s2 += v.x * v.x + v.y * v.y + v.z * v.z + v.w * v.w;
            float p = v.x * gm.x + v.y * gm.y + v.z * gm.z + v.w * gm.w;
            p += __shfl_xor(p, 1);
            p += __shfl_xor(p, 2);
            p += __shfl_xor(p, 4);
            if (n4 == 0) smem[ch] = p;        // one writer per 8-lane cluster
        }
        float bsum = beta[t];                 // 1024 threads cover beta exactly
        #pragma unroll
        for (int m = 1; m < 64; m <<= 1) {
            s1 += __shfl_xor(s1, m); s2 += __shfl_xor(s2, m); bsum += __shfl_xor(bsum, m);
        }
        if (lane == 0) { r1[wave] = s1; r2[wave] = s2; rb[wave] = bsum; }
        __syncthreads();

        float S1 = 0.f, S2 = 0.f, SB = 0.f;
        #pragma unroll
        for (int w = 0; w < 16; w++) { S1 += r1[w]; S2 += r2[w]; SB += rb[w]; }
        const float mean = S1 * (1.f / EPG);
        const float var  = S2 * (1.f / EPG) - mean * mean;
        const float inv  = rsqrtf(var + EPSV);
        float sg = gm.x + gm.y + gm.z + gm.w;   // this group's 32 gammas
        sg += __shfl_xor(sg, 1);
        sg += __shfl_xor(sg, 2);
        sg += __shfl_xor(sg, 4);
        const float cshare = SB * (1.f / 32.f) - inv * mean * sg;

        atomicAdd(&colsum[b * CH + t], inv * smem[t] + cshare);  // one per thread
    }
    batch_barrier(&bar0[b * 32], G);   // wait for the 32 g-blocks of THIS batch

    // ---- phase 2: S[b,d] = dot(Wv[d,:], colsum[b,:]) + 1024*bv[d] ----
    // Block = (b, rowgroup rg) -> rows d = rg*32..rg*32+31 (2 rows per wave).
    // Only 4 KB of coherent loads per block (colsum[b,:] -> LDS); Wv rows are
    // normal cached loads (16x reuse across the 16 b-blocks per rowgroup).
    {
        const int rg = blk & 31;
        if (t < 512) {
            float a0, a1;
            coh_load_f32x2(colsum + b * CH + t * 2, &a0, &a1);
            smem[t * 2 + 0] = a0; smem[t * 2 + 1] = a1;
        }
        __syncthreads();

        const int d0 = rg * 32 + wave * 2;
        const float4* cs4 = reinterpret_cast<const float4*>(smem);
        #pragma unroll
        for (int j = 0; j < 2; j++) {
            const int d = d0 + j;
            const float4* wrow = reinterpret_cast<const float4*>(Wv + (size_t)d * CH);
            float a = 0.f;
            #pragma unroll
            for (int i = 0; i < 4; i++) {
                int e4 = i * 64 + lane;
                float4 w = wrow[e4];
                float4 c = cs4[e4];
                a += w.x * c.x + w.y * c.y + w.z * c.z + w.w * c.w;
            }
            #pragma unroll
            for (int m = 1; m < 64; m <<= 1) a += __shfl_xor(a, m);
            if (lane == 0)
                coh_store_f32(&S[b * CH + d], a + (float)NHW * bv[d]);  // write-through
        }
    }
    batch_barrier(&bar1[b * 32], G);   // wait for the 32 rg-blocks of THIS batch

    // ---- phase 3: out[b,d,:] = dot(Wo[d,:], S[b,:]) + bo[d], bcast over hw ----
    // Same partition; coherent-load S[b,:] (4 KB) to LDS; Wo cached; out
    // written with plain stores (flushed at kernel end).
    {
        const int rg = blk & 31;
        if (t < 512) {
            float a0, a1;
            coh_load_f32x2(S + b * CH + t * 2, &a0, &a1);
            smem[t * 2 + 0] = a0; smem[t * 2 + 1] = a1;
        }
        __syncthreads();

        const int d0 = rg * 32 + wave * 2;
        const float4* s4 = reinterpret_cast<const float4*>(smem);
        #pragma unroll
        for (int j = 0; j < 2; j++) {
            const int d = d0 + j;
            const float4* wrow = reinterpret_cast<const float4*>(Wo + (size_t)d * CH);
            float a = 0.f;
            #pragma unroll
            for (int i = 0; i < 4; i++) {
                int e4 = i * 64 + lane;
                float4 w = wrow[e4];
                float4 c = s4[e4];
                a += w.x * c.x + w.y * c.y + w.z * c.z + w.w * c.w;
            }
            #pragma unroll
            for (int m = 1; m < 64; m <<= 1) a += __shfl_xor(a, m);  // all lanes hold sum
            const float val = a + bo[d];
            float4 v4 = make_float4(val, val, val, val);
            float4* op = reinterpret_cast<float4*>(out + ((size_t)b * CH + d) * NHW);
            #pragma unroll
            for (int i = 0; i < 4; i++) op[i * 64 + lane] = v4;  // 1 KiB contiguous per wave-store
        }
    }
}

extern "C" void kernel_launch(void* const* d_in, const int* in_sizes, int n_in,
                              void* d_out, int out_size, void* d_ws, size_t ws_size,
                              hipStream_t stream)
{
    const float* x     = (const float*)d_in[0];
    const float* gamma = (const float*)d_in[1];
    const float* beta  = (const float*)d_in[2];
    // d_in[3..6] = Wq, bq, Wk, bk: provably dead (softmax row-sum == 1)
    const float* Wv    = (const float*)d_in[7];
    const float* bv    = (const float*)d_in[8];
    const float* Wo    = (const float*)d_in[9];
    const float* bo    = (const float*)d_in[10];
    float* out = (float*)d_out;

    char* ws = (char*)d_ws;
    float* colsum = (float*)ws;                       // 16*1024 f = 64 KiB
    int*   bar0   = (int*)(ws + 65536);               // 16 counters, 128B apart
    int*   bar1   = (int*)(ws + 65536 + 2048);        // 16 counters, 128B apart
    float* Sbuf   = (float*)(ws + 65536 + 4096);      // 16*1024 f = 64 KiB

    // One memset zeroes colsum AND all barrier counters.
    hipMemsetAsync(ws, 0, 65536 + 4096, stream);
    fused_all<<<GRID, TPB, 0, stream>>>(x, gamma, beta, Wv, bv, Wo, bo,
                                        colsum, Sbuf, out, bar0, bar1);
}